// Round 10
// baseline (347.870 us; speedup 1.0000x reference)
//
#include <hip/hip_runtime.h>
#include <hip/hip_bf16.h>
#include <stdint.h>

#define NROWS   65536
#define EPS     1e-5f
#define BM      32
#define NBLK    (NROWS / BM)   // 2048

typedef __attribute__((ext_vector_type(8))) short short8;
typedef __attribute__((ext_vector_type(4))) float f32x4;
typedef __attribute__((ext_vector_type(16))) float f32x16;

__device__ __forceinline__ unsigned short f2bf(float f) {
    unsigned u = __float_as_uint(f);
    unsigned r = (u + 0x7FFFu + ((u >> 16) & 1u)) >> 16;
    return (unsigned short)r;
}

// LDS cell addressing: k-packed cells of 8 bf16 (16 B), cell(kg, r) for 32 rows,
// XOR-swizzled. Unchanged from R4/R9 (writer+reader agree).
__device__ __forceinline__ int cellb(int kg, int r) {
    return (((kg << 5) + r) << 4) ^ ((kg & 3) << 5);
}

// ---------------- K0: weights -> bf16, 32x32-MFMA-fragment-packed ----------------
// Fragment order: [tile=n>>5][kt=k>>4][lane][j], elem: n = tile*32+(l&31),
// k = kt*16+(l>>5)*8+j.  Chunk (tile,kt) = 512 contiguous elems (1 KB).
__global__ void k_prep(const float* __restrict__ W1, const float* __restrict__ W2,
                       const float* __restrict__ W3,
                       unsigned short* __restrict__ w1p, unsigned short* __restrict__ w2p,
                       unsigned short* __restrict__ w3p) {
    int idx = blockIdx.x * 256 + threadIdx.x;
    if (idx < 131072) {                      // W1: K=256 (kt 0..15), N=512 (tile 0..15)
        int j = idx & 7, l = (idx >> 3) & 63, kt = (idx >> 9) & 15, tile = idx >> 13;
        int n = tile * 32 + (l & 31);
        int k = kt * 16 + (l >> 5) * 8 + j;
        w1p[idx] = f2bf(W1[k * 512 + n]);
    } else if (idx < 393216) {               // W2: K=512 (kt 0..31), N=512 (tile 0..15)
        int i2 = idx - 131072;
        int j = i2 & 7, l = (i2 >> 3) & 63, kt = (i2 >> 9) & 31, tile = i2 >> 14;
        int n = tile * 32 + (l & 31);
        int k = kt * 16 + (l >> 5) * 8 + j;
        w2p[i2] = f2bf(W2[k * 512 + n]);
    } else if (idx < 524288) {               // W3: K=512 (kt 0..31), N=256 (tile 0..7)
        int i3 = idx - 393216;
        int j = i3 & 7, l = (i3 >> 3) & 63, kt = (i3 >> 9) & 31, tile = i3 >> 14;
        int n = tile * 32 + (l & 31);
        int k = kt * 16 + (l >> 5) * 8 + j;
        w3p[i3] = f2bf(W3[k * 256 + n]);
    }
}

// ---------------- K1: fused MLP chain (32x32x16 MFMA) ----------------
// 2048 blocks x 512 thr (8 waves), block owns 32 batch rows (R4/R9 geometry —
// only spill-free point of R2-R8; do not change without re-budgeting).
// Wave w owns cols [w*64, w*64+64) = 2 col-tiles of 32 (layers 1-2);
// layer3: 1 tile of 32 cols.
// A-frag (32x32x16): lane l -> row l&31, k-chunk l>>5. C/D: col=l&31,
// row=(reg&3)+8*(reg>>2)+4*(l>>5)  [m74/m101 verified].
// LDS: h1s 32 KB [0,32K), ebuf 16 KB [32K,48K). zbuf (fp32 32KB) aliases h1s.
// Pipeline (R9): 1-deep A+B double-buffer; regs: agg 32 + c 32 + A 16 + B 32
// + misc ~16 = ~128 cap. B-frags DIRECT from L2 (R5: LDS-staging = 2.3x worse).
__global__ __launch_bounds__(512, 2)
void k_fused(const float* __restrict__ x,
             const unsigned short* __restrict__ w1p,
             const unsigned short* __restrict__ w2p,
             const unsigned short* __restrict__ w3p,
             const float* __restrict__ b1, const float* __restrict__ b2,
             const float* __restrict__ b3,
             float* __restrict__ out,
             float* __restrict__ psum, float* __restrict__ psumsq) {
    __shared__ __align__(16) unsigned char smem[49152];
    unsigned char* h1b = smem;            // 32 KB
    unsigned char* ebb = smem + 32768;    // 16 KB
    float* zbuf = (float*)smem;

    const int tid = threadIdx.x;
    const int w   = tid >> 6;
    const int l   = tid & 63;
    const int l31 = l & 31;
    const int hl  = l >> 5;       // 0..1: k-chunk half
    const int blk = blockIdx.x;
    const int row0 = blk * BM;

    // staging mapping: row = tid&31, kg-chunk = tid>>5 (0..15), 2 cells/thread
    const int sr  = tid & 31;
    const int skg = tid >> 5;
    const float* xrow = x + (size_t)(row0 + sr) * 768;

    // hoisted biases (per col-tile, col = tile*32 + l31)
    float bias1[2], bias2[2];
#pragma unroll
    for (int ct = 0; ct < 2; ++ct) {
        bias1[ct] = b1[(w * 2 + ct) * 32 + l31];
        bias2[ct] = b2[(w * 2 + ct) * 32 + l31];
    }
    const float bias3 = b3[w * 32 + l31];

    f32x16 agg[2];
#pragma unroll
    for (int ct = 0; ct < 2; ++ct)
#pragma unroll
        for (int r = 0; r < 16; ++r) agg[ct][r] = 0.f;

    for (int e = 0; e < 3; ++e) {
        const int na = e >> 1;              // 0,0,1
        const int nb = ((e + 1) >> 1) + 1;  // 1,2,2

        // ---- stage e = x[na] + x[nb] into ebuf (bf16, k-packed) ----
#pragma unroll
        for (int h = 0; h < 2; ++h) {
            int kg = skg + h * 16;
            const float* pa = xrow + na * 256 + kg * 8;
            const float* pb = xrow + nb * 256 + kg * 8;
            float4 a0 = *(const float4*)(pa);
            float4 a1 = *(const float4*)(pa + 4);
            float4 bv0 = *(const float4*)(pb);
            float4 bv1 = *(const float4*)(pb + 4);
            uint4 pk;
            pk.x = (unsigned)f2bf(a0.x + bv0.x) | ((unsigned)f2bf(a0.y + bv0.y) << 16);
            pk.y = (unsigned)f2bf(a0.z + bv0.z) | ((unsigned)f2bf(a0.w + bv0.w) << 16);
            pk.z = (unsigned)f2bf(a1.x + bv1.x) | ((unsigned)f2bf(a1.y + bv1.y) << 16);
            pk.w = (unsigned)f2bf(a1.z + bv1.z) | ((unsigned)f2bf(a1.w + bv1.w) << 16);
            *(uint4*)(ebb + cellb(kg, sr)) = pk;
        }
        __syncthreads();   // ebuf ready; orders prev-edge h1s reads vs epilogue below

        // ---- layer1: c1 = e @ W1  (K=256, 8 steps of K=32, 1-deep pipeline) ----
        f32x16 c1[2];
#pragma unroll
        for (int ct = 0; ct < 2; ++ct)
#pragma unroll
            for (int r = 0; r < 16; ++r) c1[ct][r] = 0.f;

        {
            short8 aC[2], aN[2], bC[2][2], bN[2][2];
#pragma unroll
            for (int s = 0; s < 2; ++s) {
                aC[s] = *(const short8*)(ebb + cellb(s * 2 + hl, l31));
#pragma unroll
                for (int ct = 0; ct < 2; ++ct)
                    bC[ct][s] = *(const short8*)(w1p + (((w * 2 + ct) * 16 + s) * 64 + l) * 8);
            }
#pragma unroll 2
            for (int kt = 0; kt < 8; ++kt) {
                if (kt < 7) {
#pragma unroll
                    for (int s = 0; s < 2; ++s) {
                        aN[s] = *(const short8*)(ebb + cellb((kt + 1) * 4 + s * 2 + hl, l31));
#pragma unroll
                        for (int ct = 0; ct < 2; ++ct)
                            bN[ct][s] = *(const short8*)(w1p + (((w * 2 + ct) * 16 + (kt + 1) * 2 + s) * 64 + l) * 8);
                    }
                }
                __builtin_amdgcn_s_setprio(1);
#pragma unroll
                for (int ct = 0; ct < 2; ++ct)
#pragma unroll
                    for (int s = 0; s < 2; ++s)
                        c1[ct] = __builtin_amdgcn_mfma_f32_32x32x16_bf16(aC[s], bC[ct][s], c1[ct], 0, 0, 0);
                __builtin_amdgcn_s_setprio(0);
#pragma unroll
                for (int s = 0; s < 2; ++s) {
                    aC[s] = aN[s];
#pragma unroll
                    for (int ct = 0; ct < 2; ++ct) bC[ct][s] = bN[ct][s];
                }
            }
        }

        // ---- layer1 epilogue: relu(c1+b1) -> h1s (bf16, k-packed) ----
#pragma unroll
        for (int ct = 0; ct < 2; ++ct) {
            int c = (w * 2 + ct) * 32 + l31;
#pragma unroll
            for (int reg = 0; reg < 16; ++reg) {
                int r = (reg & 3) + 8 * (reg >> 2) + 4 * hl;
                float v = c1[ct][reg] + bias1[ct];
                v = v > 0.f ? v : 0.f;
                *(unsigned short*)(h1b + cellb(c >> 3, r) + ((c & 7) << 1)) = f2bf(v);
            }
        }
        __syncthreads();   // h1s ready; ebuf reads done -> next stage may overwrite

        // ---- layer2: c2 = h1 @ W2  (K=512, 16 steps of K=32, pipelined) ----
        f32x16 c2[2];
#pragma unroll
        for (int ct = 0; ct < 2; ++ct)
#pragma unroll
            for (int r = 0; r < 16; ++r) c2[ct][r] = 0.f;

        {
            short8 aC[2], aN[2], bC[2][2], bN[2][2];
#pragma unroll
            for (int s = 0; s < 2; ++s) {
                aC[s] = *(const short8*)(h1b + cellb(s * 2 + hl, l31));
#pragma unroll
                for (int ct = 0; ct < 2; ++ct)
                    bC[ct][s] = *(const short8*)(w2p + (((w * 2 + ct) * 32 + s) * 64 + l) * 8);
            }
#pragma unroll 2
            for (int kt = 0; kt < 16; ++kt) {
                if (kt < 15) {
#pragma unroll
                    for (int s = 0; s < 2; ++s) {
                        aN[s] = *(const short8*)(h1b + cellb((kt + 1) * 4 + s * 2 + hl, l31));
#pragma unroll
                        for (int ct = 0; ct < 2; ++ct)
                            bN[ct][s] = *(const short8*)(w2p + (((w * 2 + ct) * 32 + (kt + 1) * 2 + s) * 64 + l) * 8);
                    }
                }
                __builtin_amdgcn_s_setprio(1);
#pragma unroll
                for (int ct = 0; ct < 2; ++ct)
#pragma unroll
                    for (int s = 0; s < 2; ++s)
                        c2[ct] = __builtin_amdgcn_mfma_f32_32x32x16_bf16(aC[s], bC[ct][s], c2[ct], 0, 0, 0);
                __builtin_amdgcn_s_setprio(0);
#pragma unroll
                for (int s = 0; s < 2; ++s) {
                    aC[s] = aN[s];
#pragma unroll
                    for (int ct = 0; ct < 2; ++ct) bC[ct][s] = bN[ct][s];
                }
            }
        }

        // ---- relu(c2+b2) accumulated into agg (registers) ----
#pragma unroll
        for (int ct = 0; ct < 2; ++ct)
#pragma unroll
            for (int reg = 0; reg < 16; ++reg) {
                float v = c2[ct][reg] + bias2[ct];
                agg[ct][reg] += (v > 0.f ? v : 0.f);
            }
        // next edge's post-stage barrier orders the h1s overwrite
    }

    // ---- agg -> h1s (bf16, k-packed) ----
    __syncthreads();   // all waves done reading h1s in layer2
#pragma unroll
    for (int ct = 0; ct < 2; ++ct) {
        int c = (w * 2 + ct) * 32 + l31;
#pragma unroll
        for (int reg = 0; reg < 16; ++reg) {
            int r = (reg & 3) + 8 * (reg >> 2) + 4 * hl;
            *(unsigned short*)(h1b + cellb(c >> 3, r) + ((c & 7) << 1)) = f2bf(agg[ct][reg]);
        }
    }
    __syncthreads();

    // ---- layer3: z = agg @ W3 + b3  (K=512, wave owns 32 cols, pipelined) ----
    f32x16 c3;
#pragma unroll
    for (int r = 0; r < 16; ++r) c3[r] = 0.f;

    {
        short8 aC[2], aN[2], bC[2], bN[2];
#pragma unroll
        for (int s = 0; s < 2; ++s) {
            aC[s] = *(const short8*)(h1b + cellb(s * 2 + hl, l31));
            bC[s] = *(const short8*)(w3p + ((w * 32 + s) * 64 + l) * 8);
        }
#pragma unroll 2
        for (int kt = 0; kt < 16; ++kt) {
            if (kt < 15) {
#pragma unroll
                for (int s = 0; s < 2; ++s) {
                    aN[s] = *(const short8*)(h1b + cellb((kt + 1) * 4 + s * 2 + hl, l31));
                    bN[s] = *(const short8*)(w3p + ((w * 32 + (kt + 1) * 2 + s) * 64 + l) * 8);
                }
            }
            __builtin_amdgcn_s_setprio(1);
#pragma unroll
            for (int s = 0; s < 2; ++s)
                c3 = __builtin_amdgcn_mfma_f32_32x32x16_bf16(aC[s], bC[s], c3, 0, 0, 0);
            __builtin_amdgcn_s_setprio(0);
#pragma unroll
            for (int s = 0; s < 2; ++s) { aC[s] = aN[s]; bC[s] = bN[s]; }
        }
    }

    // ---- z epilogue: zbuf (aliases h1s) for coalesced stores + BN partials ----
    __syncthreads();   // layer3 ds_reads done before overwriting as zbuf
    {
        int c = w * 32 + l31;
        float s = 0.f, q = 0.f;
#pragma unroll
        for (int reg = 0; reg < 16; ++reg) {
            int r = (reg & 3) + 8 * (reg >> 2) + 4 * hl;
            float v = c3[reg] + bias3;
            zbuf[r * 256 + c] = v;
            s += v;
            q += v * v;
        }
        // lanes l and l+32 hold disjoint row-halves of col c
        s += __shfl_xor(s, 32);
        q += __shfl_xor(q, 32);
        if (hl == 0) {
            psum[c * NBLK + blk] = s;
            psumsq[c * NBLK + blk] = q;
        }
    }
    __syncthreads();
    {
        const float4* zb4 = (const float4*)zbuf;
        float4* o4 = (float4*)(out + (size_t)row0 * 256);
#pragma unroll
        for (int i = 0; i < 4; ++i)
            o4[tid + i * 512] = zb4[tid + i * 512];
    }
}

// ---------------- K2: reduce 2048 partials -> scale/shift ----------------
__global__ void k_stats2(const float* __restrict__ psum, const float* __restrict__ psumsq,
                         const float* __restrict__ gamma, const float* __restrict__ beta,
                         float* __restrict__ scale, float* __restrict__ shift) {
    int f = blockIdx.x, t = threadIdx.x;
    const float* ps = psum + f * NBLK;
    const float* pq = psumsq + f * NBLK;
    float s = 0.f, q = 0.f;
#pragma unroll
    for (int i = 0; i < 8; ++i) {
        s += ps[t + i * 256];
        q += pq[t + i * 256];
    }
#pragma unroll
    for (int o = 32; o > 0; o >>= 1) {
        s += __shfl_down(s, o);
        q += __shfl_down(q, o);
    }
    __shared__ float ls[4], lq[4];
    if ((t & 63) == 0) { ls[t >> 6] = s; lq[t >> 6] = q; }
    __syncthreads();
    if (t == 0) {
        s = ls[0] + ls[1] + ls[2] + ls[3];
        q = lq[0] + lq[1] + lq[2] + lq[3];
        float mu  = s * (1.f / 65536.f);
        float var = q * (1.f / 65536.f) - mu * mu;
        float sc  = gamma[f] * rsqrtf(var + EPS);
        scale[f] = sc;
        shift[f] = beta[f] - mu * sc;
    }
}

// ---------------- K3: in-place normalize of d_out ----------------
__global__ void k_norm(float4* __restrict__ out4, const float4* __restrict__ scale4,
                       const float4* __restrict__ shift4, int n4) {
    int i = blockIdx.x * blockDim.x + threadIdx.x;
    int stride = gridDim.x * blockDim.x;
    for (; i < n4; i += stride) {
        float4 v = out4[i];
        float4 sc = scale4[i & 63];
        float4 sh = shift4[i & 63];
        v.x = v.x * sc.x + sh.x;
        v.y = v.y * sc.y + sh.y;
        v.z = v.z * sc.z + sh.z;
        v.w = v.w * sc.w + sh.w;
        out4[i] = v;
    }
}

extern "C" void kernel_launch(void* const* d_in, const int* in_sizes, int n_in,
                              void* d_out, int out_size, void* d_ws, size_t ws_size,
                              hipStream_t stream) {
    const float* x     = (const float*)d_in[0];
    const float* W1    = (const float*)d_in[1];
    const float* b1    = (const float*)d_in[2];
    const float* W2    = (const float*)d_in[3];
    const float* b2    = (const float*)d_in[4];
    const float* W3    = (const float*)d_in[5];
    const float* b3    = (const float*)d_in[6];
    const float* gamma = (const float*)d_in[7];
    const float* beta  = (const float*)d_in[8];

    char* ws = (char*)d_ws;
    unsigned short* w1p = (unsigned short*)(ws);            // 256 KB
    unsigned short* w2p = (unsigned short*)(ws + 262144);   // 512 KB
    unsigned short* w3p = (unsigned short*)(ws + 786432);   // 256 KB
    float* psum   = (float*)(ws + 1048576);                 // 2 MB
    float* psumsq = (float*)(ws + 3145728);                 // 2 MB
    float* scale  = (float*)(ws + 5242880);                 // 1 KB
    float* shift  = (float*)(ws + 5243904);                 // 1 KB

    float* out = (float*)d_out;

    k_prep<<<2048, 256, 0, stream>>>(W1, W2, W3, w1p, w2p, w3p);
    k_fused<<<NBLK, 512, 0, stream>>>(x, w1p, w2p, w3p, b1, b2, b3, out, psum, psumsq);
    k_stats2<<<256, 256, 0, stream>>>(psum, psumsq, gamma, beta, scale, shift);
    k_norm<<<2048, 256, 0, stream>>>((float4*)out, (const float4*)scale, (const float4*)shift,
                                     (NROWS * 256) / 4);
}

// Round 11
// 312.988 us; speedup vs baseline: 1.1114x; 1.1114x over previous
//
#include <hip/hip_runtime.h>
#include <hip/hip_bf16.h>
#include <stdint.h>

#define NROWS   65536
#define EPS     1e-5f
#define BM      32
#define NBLK    (NROWS / BM)   // 2048

typedef __attribute__((ext_vector_type(8))) short short8;
typedef __attribute__((ext_vector_type(4))) float f32x4;

__device__ __forceinline__ unsigned short f2bf(float f) {
    unsigned u = __float_as_uint(f);
    unsigned r = (u + 0x7FFFu + ((u >> 16) & 1u)) >> 16;
    return (unsigned short)r;
}

// LDS cell addressing: k-packed cells of 8 bf16 (16 B), cell(kg, r) for 32 rows,
// XOR-swizzled so the 4 lg-chunks of an A-fragment read start at different banks.
__device__ __forceinline__ int cellb(int kg, int r) {
    return (((kg << 5) + r) << 4) ^ ((kg & 3) << 5);
}

// ---------------- K0: weights -> bf16, MFMA-fragment-packed (16x16) ----------------
// Fragment order: [tile=n>>4][kt][lane][j], elem: n = tile*16+(l&15),
// k = kt*32+(l>>4)*8+j.  A wave's B-load per K-step = contiguous 1 KB.
__global__ void k_prep(const float* __restrict__ W1, const float* __restrict__ W2,
                       const float* __restrict__ W3,
                       unsigned short* __restrict__ w1p, unsigned short* __restrict__ w2p,
                       unsigned short* __restrict__ w3p) {
    int idx = blockIdx.x * 256 + threadIdx.x;
    if (idx < 131072) {                      // W1: K=256 (kt 0..7), N=512 (tile 0..31)
        int j = idx & 7, l = (idx >> 3) & 63, kt = (idx >> 9) & 7, tile = idx >> 12;
        int n = tile * 16 + (l & 15);
        int k = kt * 32 + (l >> 4) * 8 + j;
        w1p[idx] = f2bf(W1[k * 512 + n]);
    } else if (idx < 393216) {               // W2: K=512 (kt 0..15), N=512 (tile 0..31)
        int i2 = idx - 131072;
        int j = i2 & 7, l = (i2 >> 3) & 63, kt = (i2 >> 9) & 15, tile = i2 >> 13;
        int n = tile * 16 + (l & 15);
        int k = kt * 32 + (l >> 4) * 8 + j;
        w2p[i2] = f2bf(W2[k * 512 + n]);
    } else if (idx < 524288) {               // W3: K=512 (kt 0..15), N=256 (tile 0..15)
        int i3 = idx - 393216;
        int j = i3 & 7, l = (i3 >> 3) & 63, kt = (i3 >> 9) & 15, tile = i3 >> 13;
        int n = tile * 16 + (l & 15);
        int k = kt * 32 + (l >> 4) * 8 + j;
        w3p[i3] = f2bf(W3[k * 256 + n]);
    }
}

// ---------------- K1: fused MLP chain (R9 base + ping-pong + prologue hoist) ----------------
// 2048 blocks x 512 thr (8 waves), block owns 32 batch rows (R4/R9 geometry —
// only spill-free point of R2-R8). 16x16x32 MFMA (R10: 32x32x16 was -9%, reverted).
// LDS: h1s 32 KB [0,32K), ebuf 16 KB [32K,48K). zbuf (fp32 32KB) aliases h1s.
// Pipeline: manual ping-pong (P/Q buffers, kt+=2) — no rotate copies; B-frag
// kt=0 prologue loads issued BEFORE each phase barrier (global-only, no hazard).
// Regs: agg 32 + c 32 + A 2x8 + B 2x16 + misc ~16 = ~128 cap, no spills.
// B-frags DIRECT from L2 (R5: LDS-staging weights = 2.3x worse).
__global__ __launch_bounds__(512, 2)
void k_fused(const float* __restrict__ x,
             const unsigned short* __restrict__ w1p,
             const unsigned short* __restrict__ w2p,
             const unsigned short* __restrict__ w3p,
             const float* __restrict__ b1, const float* __restrict__ b2,
             const float* __restrict__ b3,
             float* __restrict__ out,
             float* __restrict__ psum, float* __restrict__ psumsq) {
    __shared__ __align__(16) unsigned char smem[49152];
    unsigned char* h1b = smem;            // 32 KB
    unsigned char* ebb = smem + 32768;    // 16 KB
    float* zbuf = (float*)smem;

    const int tid = threadIdx.x;
    const int w   = tid >> 6;
    const int l   = tid & 63;
    const int l15 = l & 15;
    const int lg  = l >> 4;
    const int blk = blockIdx.x;
    const int row0 = blk * BM;

    // staging mapping: row = tid&31, kg-chunk = tid>>5 (0..15), 2 cells/thread
    const int sr  = tid & 31;
    const int skg = tid >> 5;
    const float* xrow = x + (size_t)(row0 + sr) * 768;

    f32x4 agg[2][4];
#pragma unroll
    for (int a = 0; a < 2; ++a)
#pragma unroll
        for (int b = 0; b < 4; ++b) agg[a][b] = (f32x4){0.f, 0.f, 0.f, 0.f};

    for (int e = 0; e < 3; ++e) {
        const int na = e >> 1;              // 0,0,1
        const int nb = ((e + 1) >> 1) + 1;  // 1,2,2

        // ---- stage e = x[na] + x[nb] into ebuf (bf16, k-packed) ----
#pragma unroll
        for (int h = 0; h < 2; ++h) {
            int kg = skg + h * 16;
            const float* pa = xrow + na * 256 + kg * 8;
            const float* pb = xrow + nb * 256 + kg * 8;
            float4 a0 = *(const float4*)(pa);
            float4 a1 = *(const float4*)(pa + 4);
            float4 bv0 = *(const float4*)(pb);
            float4 bv1 = *(const float4*)(pb + 4);
            uint4 pk;
            pk.x = (unsigned)f2bf(a0.x + bv0.x) | ((unsigned)f2bf(a0.y + bv0.y) << 16);
            pk.y = (unsigned)f2bf(a0.z + bv0.z) | ((unsigned)f2bf(a0.w + bv0.w) << 16);
            pk.z = (unsigned)f2bf(a1.x + bv1.x) | ((unsigned)f2bf(a1.y + bv1.y) << 16);
            pk.w = (unsigned)f2bf(a1.z + bv1.z) | ((unsigned)f2bf(a1.w + bv1.w) << 16);
            *(uint4*)(ebb + cellb(kg, sr)) = pk;
        }

        // ---- layer1: c1 = e @ W1  (K=256, 8 K-steps, ping-pong) ----
        f32x4 c1[2][4];
#pragma unroll
        for (int mt = 0; mt < 2; ++mt)
#pragma unroll
            for (int nt = 0; nt < 4; ++nt) c1[mt][nt] = (f32x4){0.f, 0.f, 0.f, 0.f};

        {
            short8 aP[2], aQ[2], bP[4], bQ[4];
            // B prologue pre-barrier: hides L2 latency under the barrier drain
#pragma unroll
            for (int nt = 0; nt < 4; ++nt)
                bP[nt] = *(const short8*)(w1p + (((w * 4 + nt) * 8) * 64 + l) * 8);
            __syncthreads();   // ebuf ready; orders prev-edge h1s reads vs epilogue below
#pragma unroll
            for (int mt = 0; mt < 2; ++mt)
                aP[mt] = *(const short8*)(ebb + cellb(lg, mt * 16 + l15));
#pragma unroll 1
            for (int kt = 0; kt < 8; kt += 2) {
                // prefetch kt+1 (kt <= 6, always valid)
#pragma unroll
                for (int mt = 0; mt < 2; ++mt)
                    aQ[mt] = *(const short8*)(ebb + cellb((kt + 1) * 4 + lg, mt * 16 + l15));
#pragma unroll
                for (int nt = 0; nt < 4; ++nt)
                    bQ[nt] = *(const short8*)(w1p + (((w * 4 + nt) * 8 + kt + 1) * 64 + l) * 8);
                __builtin_amdgcn_s_setprio(1);
#pragma unroll
                for (int nt = 0; nt < 4; ++nt)
#pragma unroll
                    for (int mt = 0; mt < 2; ++mt)
                        c1[mt][nt] = __builtin_amdgcn_mfma_f32_16x16x32_bf16(aP[mt], bP[nt], c1[mt][nt], 0, 0, 0);
                __builtin_amdgcn_s_setprio(0);
                if (kt + 2 < 8) {
#pragma unroll
                    for (int mt = 0; mt < 2; ++mt)
                        aP[mt] = *(const short8*)(ebb + cellb((kt + 2) * 4 + lg, mt * 16 + l15));
#pragma unroll
                    for (int nt = 0; nt < 4; ++nt)
                        bP[nt] = *(const short8*)(w1p + (((w * 4 + nt) * 8 + kt + 2) * 64 + l) * 8);
                }
                __builtin_amdgcn_s_setprio(1);
#pragma unroll
                for (int nt = 0; nt < 4; ++nt)
#pragma unroll
                    for (int mt = 0; mt < 2; ++mt)
                        c1[mt][nt] = __builtin_amdgcn_mfma_f32_16x16x32_bf16(aQ[mt], bQ[nt], c1[mt][nt], 0, 0, 0);
                __builtin_amdgcn_s_setprio(0);
            }
        }

        // ---- layer1 epilogue: relu(c1+b1) -> h1s (bf16, k-packed) ----
#pragma unroll
        for (int nt = 0; nt < 4; ++nt) {
            int c = w * 64 + nt * 16 + l15;
            float bias = b1[c];
#pragma unroll
            for (int mt = 0; mt < 2; ++mt)
#pragma unroll
                for (int reg = 0; reg < 4; ++reg) {
                    int r = mt * 16 + lg * 4 + reg;
                    float v = c1[mt][nt][reg] + bias;
                    v = v > 0.f ? v : 0.f;
                    *(unsigned short*)(h1b + cellb(c >> 3, r) + ((c & 7) << 1)) = f2bf(v);
                }
        }

        // ---- layer2: c2 = h1 @ W2  (K=512, 16 K-steps, ping-pong) ----
        f32x4 c2[2][4];
#pragma unroll
        for (int mt = 0; mt < 2; ++mt)
#pragma unroll
            for (int nt = 0; nt < 4; ++nt) c2[mt][nt] = (f32x4){0.f, 0.f, 0.f, 0.f};

        {
            short8 aP[2], aQ[2], bP[4], bQ[4];
#pragma unroll
            for (int nt = 0; nt < 4; ++nt)
                bP[nt] = *(const short8*)(w2p + (((w * 4 + nt) * 16) * 64 + l) * 8);
            __syncthreads();   // h1s ready; ebuf reads done -> next stage may overwrite
#pragma unroll
            for (int mt = 0; mt < 2; ++mt)
                aP[mt] = *(const short8*)(h1b + cellb(lg, mt * 16 + l15));
#pragma unroll 1
            for (int kt = 0; kt < 16; kt += 2) {
#pragma unroll
                for (int mt = 0; mt < 2; ++mt)
                    aQ[mt] = *(const short8*)(h1b + cellb((kt + 1) * 4 + lg, mt * 16 + l15));
#pragma unroll
                for (int nt = 0; nt < 4; ++nt)
                    bQ[nt] = *(const short8*)(w2p + (((w * 4 + nt) * 16 + kt + 1) * 64 + l) * 8);
                __builtin_amdgcn_s_setprio(1);
#pragma unroll
                for (int nt = 0; nt < 4; ++nt)
#pragma unroll
                    for (int mt = 0; mt < 2; ++mt)
                        c2[mt][nt] = __builtin_amdgcn_mfma_f32_16x16x32_bf16(aP[mt], bP[nt], c2[mt][nt], 0, 0, 0);
                __builtin_amdgcn_s_setprio(0);
                if (kt + 2 < 16) {
#pragma unroll
                    for (int mt = 0; mt < 2; ++mt)
                        aP[mt] = *(const short8*)(h1b + cellb((kt + 2) * 4 + lg, mt * 16 + l15));
#pragma unroll
                    for (int nt = 0; nt < 4; ++nt)
                        bP[nt] = *(const short8*)(w2p + (((w * 4 + nt) * 16 + kt + 2) * 64 + l) * 8);
                }
                __builtin_amdgcn_s_setprio(1);
#pragma unroll
                for (int nt = 0; nt < 4; ++nt)
#pragma unroll
                    for (int mt = 0; mt < 2; ++mt)
                        c2[mt][nt] = __builtin_amdgcn_mfma_f32_16x16x32_bf16(aQ[mt], bQ[nt], c2[mt][nt], 0, 0, 0);
                __builtin_amdgcn_s_setprio(0);
            }
        }

        // ---- relu(c2+b2) accumulated into agg (registers) ----
#pragma unroll
        for (int nt = 0; nt < 4; ++nt) {
            float bias = b2[w * 64 + nt * 16 + l15];
#pragma unroll
            for (int mt = 0; mt < 2; ++mt)
#pragma unroll
                for (int reg = 0; reg < 4; ++reg) {
                    float v = c2[mt][nt][reg] + bias;
                    agg[mt][nt][reg] += (v > 0.f ? v : 0.f);
                }
        }
        // next edge's post-stage barrier orders the h1s overwrite
    }

    // ---- agg -> h1s (bf16, k-packed) ----
    __syncthreads();   // all waves done reading h1s in layer2
#pragma unroll
    for (int nt = 0; nt < 4; ++nt) {
        int c = w * 64 + nt * 16 + l15;
#pragma unroll
        for (int mt = 0; mt < 2; ++mt)
#pragma unroll
            for (int reg = 0; reg < 4; ++reg) {
                int r = mt * 16 + lg * 4 + reg;
                *(unsigned short*)(h1b + cellb(c >> 3, r) + ((c & 7) << 1)) = f2bf(agg[mt][nt][reg]);
            }
    }

    // ---- layer3: z = agg @ W3 + b3  (K=512, wave owns 32 cols, ping-pong) ----
    f32x4 c3[2][2];
#pragma unroll
    for (int mt = 0; mt < 2; ++mt)
#pragma unroll
        for (int nt = 0; nt < 2; ++nt) c3[mt][nt] = (f32x4){0.f, 0.f, 0.f, 0.f};

    {
        short8 aP[2], aQ[2], bP[2], bQ[2];
#pragma unroll
        for (int nt = 0; nt < 2; ++nt)
            bP[nt] = *(const short8*)(w3p + (((w * 2 + nt) * 16) * 64 + l) * 8);
        __syncthreads();   // h1s(agg) ready
#pragma unroll
        for (int mt = 0; mt < 2; ++mt)
            aP[mt] = *(const short8*)(h1b + cellb(lg, mt * 16 + l15));
#pragma unroll 1
        for (int kt = 0; kt < 16; kt += 2) {
#pragma unroll
            for (int mt = 0; mt < 2; ++mt)
                aQ[mt] = *(const short8*)(h1b + cellb((kt + 1) * 4 + lg, mt * 16 + l15));
#pragma unroll
            for (int nt = 0; nt < 2; ++nt)
                bQ[nt] = *(const short8*)(w3p + (((w * 2 + nt) * 16 + kt + 1) * 64 + l) * 8);
            __builtin_amdgcn_s_setprio(1);
#pragma unroll
            for (int nt = 0; nt < 2; ++nt)
#pragma unroll
                for (int mt = 0; mt < 2; ++mt)
                    c3[mt][nt] = __builtin_amdgcn_mfma_f32_16x16x32_bf16(aP[mt], bP[nt], c3[mt][nt], 0, 0, 0);
            __builtin_amdgcn_s_setprio(0);
            if (kt + 2 < 16) {
#pragma unroll
                for (int mt = 0; mt < 2; ++mt)
                    aP[mt] = *(const short8*)(h1b + cellb((kt + 2) * 4 + lg, mt * 16 + l15));
#pragma unroll
                for (int nt = 0; nt < 2; ++nt)
                    bP[nt] = *(const short8*)(w3p + (((w * 2 + nt) * 16 + kt + 2) * 64 + l) * 8);
            }
            __builtin_amdgcn_s_setprio(1);
#pragma unroll
            for (int nt = 0; nt < 2; ++nt)
#pragma unroll
                for (int mt = 0; mt < 2; ++mt)
                    c3[mt][nt] = __builtin_amdgcn_mfma_f32_16x16x32_bf16(aQ[mt], bQ[nt], c3[mt][nt], 0, 0, 0);
            __builtin_amdgcn_s_setprio(0);
        }
    }

    // ---- z epilogue: zbuf (aliases h1s) for coalesced stores + BN partials ----
    __syncthreads();   // layer3 ds_reads done before overwriting as zbuf
#pragma unroll
    for (int nt = 0; nt < 2; ++nt) {
        int c = w * 32 + nt * 16 + l15;
        float bias = b3[c];
        float s = 0.f, q = 0.f;
#pragma unroll
        for (int mt = 0; mt < 2; ++mt)
#pragma unroll
            for (int reg = 0; reg < 4; ++reg) {
                int r = mt * 16 + lg * 4 + reg;
                float v = c3[mt][nt][reg] + bias;
                zbuf[r * 256 + c] = v;
                s += v;
                q += v * v;
            }
        // lanes {l15, l15+16, l15+32, l15+48} hold disjoint row-groups of col c
        s += __shfl_xor(s, 16); s += __shfl_xor(s, 32);
        q += __shfl_xor(q, 16); q += __shfl_xor(q, 32);
        if (lg == 0) {
            psum[c * NBLK + blk] = s;
            psumsq[c * NBLK + blk] = q;
        }
    }
    __syncthreads();
    {
        const float4* zb4 = (const float4*)zbuf;
        float4* o4 = (float4*)(out + (size_t)row0 * 256);
#pragma unroll
        for (int i = 0; i < 4; ++i)
            o4[tid + i * 512] = zb4[tid + i * 512];
    }
}

// ---------------- K2: reduce 2048 partials -> scale/shift ----------------
__global__ void k_stats2(const float* __restrict__ psum, const float* __restrict__ psumsq,
                         const float* __restrict__ gamma, const float* __restrict__ beta,
                         float* __restrict__ scale, float* __restrict__ shift) {
    int f = blockIdx.x, t = threadIdx.x;
    const float* ps = psum + f * NBLK;
    const float* pq = psumsq + f * NBLK;
    float s = 0.f, q = 0.f;
#pragma unroll
    for (int i = 0; i < 8; ++i) {
        s += ps[t + i * 256];
        q += pq[t + i * 256];
    }
#pragma unroll
    for (int o = 32; o > 0; o >>= 1) {
        s += __shfl_down(s, o);
        q += __shfl_down(q, o);
    }
    __shared__ float ls[4], lq[4];
    if ((t & 63) == 0) { ls[t >> 6] = s; lq[t >> 6] = q; }
    __syncthreads();
    if (t == 0) {
        s = ls[0] + ls[1] + ls[2] + ls[3];
        q = lq[0] + lq[1] + lq[2] + lq[3];
        float mu  = s * (1.f / 65536.f);
        float var = q * (1.f / 65536.f) - mu * mu;
        float sc  = gamma[f] * rsqrtf(var + EPS);
        scale[f] = sc;
        shift[f] = beta[f] - mu * sc;
    }
}

// ---------------- K3: in-place normalize of d_out ----------------
__global__ void k_norm(float4* __restrict__ out4, const float4* __restrict__ scale4,
                       const float4* __restrict__ shift4, int n4) {
    int i = blockIdx.x * blockDim.x + threadIdx.x;
    int stride = gridDim.x * blockDim.x;
    for (; i < n4; i += stride) {
        float4 v = out4[i];
        float4 sc = scale4[i & 63];
        float4 sh = shift4[i & 63];
        v.x = v.x * sc.x + sh.x;
        v.y = v.y * sc.y + sh.y;
        v.z = v.z * sc.z + sh.z;
        v.w = v.w * sc.w + sh.w;
        out4[i] = v;
    }
}

extern "C" void kernel_launch(void* const* d_in, const int* in_sizes, int n_in,
                              void* d_out, int out_size, void* d_ws, size_t ws_size,
                              hipStream_t stream) {
    const float* x     = (const float*)d_in[0];
    const float* W1    = (const float*)d_in[1];
    const float* b1    = (const float*)d_in[2];
    const float* W2    = (const float*)d_in[3];
    const float* b2    = (const float*)d_in[4];
    const float* W3    = (const float*)d_in[5];
    const float* b3    = (const float*)d_in[6];
    const float* gamma = (const float*)d_in[7];
    const float* beta  = (const float*)d_in[8];

    char* ws = (char*)d_ws;
    unsigned short* w1p = (unsigned short*)(ws);            // 256 KB
    unsigned short* w2p = (unsigned short*)(ws + 262144);   // 512 KB
    unsigned short* w3p = (unsigned short*)(ws + 786432);   // 256 KB
    float* psum   = (float*)(ws + 1048576);                 // 2 MB
    float* psumsq = (float*)(ws + 3145728);                 // 2 MB
    float* scale  = (float*)(ws + 5242880);                 // 1 KB
    float* shift  = (float*)(ws + 5243904);                 // 1 KB

    float* out = (float*)d_out;

    k_prep<<<2048, 256, 0, stream>>>(W1, W2, W3, w1p, w2p, w3p);
    k_fused<<<NBLK, 512, 0, stream>>>(x, w1p, w2p, w3p, b1, b2, b3, out, psum, psumsq);
    k_stats2<<<256, 256, 0, stream>>>(psum, psumsq, gamma, beta, scale, shift);
    k_norm<<<2048, 256, 0, stream>>>((float4*)out, (const float4*)scale, (const float4*)shift,
                                     (NROWS * 256) / 4);
}